// Round 11
// baseline (474.105 us; speedup 1.0000x reference)
//
#include <hip/hip_runtime.h>
#include <math.h>

#define BB   32
#define HHI  56
#define WWI  56
#define CC   256
#define LL   3136      // H*W
#define SS   16
#define NCH  56        // chunks per batch
#define CHL  56        // chunk length
#define NSL  98        // spatial slices for reductions (32 positions each)
#define EPSV 1e-5f

typedef float vfloat4 __attribute__((ext_vector_type(4)));

__device__ __forceinline__ float softplusf(float z) {
    return fmaxf(z, 0.f) + __logf(1.f + __expf(-fabsf(z)));
}
__device__ __forceinline__ float sigmoidf(float z) {
    return 1.f / (1.f + __expf(-z));
}

// -------------------- K1: CA partials + last-block FC ---------------------
// grid (32,98), block 256. Each block reduces 32 positions; the 98th block
// to finish for batch b performs the FC and writes gate[b][:].
__global__ void k_ca(const float* __restrict__ x,
                     const float* __restrict__ w1, const float* __restrict__ w2,
                     float* __restrict__ psum, float* __restrict__ pmax,
                     float* __restrict__ gate, unsigned* __restrict__ cnt) {
    const int b = blockIdx.x, sl = blockIdx.y;
    const int wv = threadIdx.x >> 6, l = threadIdx.x & 63;
    const float4* x4 = (const float4*)x;
    const size_t base = ((size_t)b * LL + sl * 32) * 64;
    float4 s  = make_float4(0.f, 0.f, 0.f, 0.f);
    float4 mx = make_float4(-1e30f, -1e30f, -1e30f, -1e30f);
#pragma unroll
    for (int k = 0; k < 8; k++) {
        float4 v = x4[base + (size_t)(k * 4 + wv) * 64 + l];
        s.x += v.x; s.y += v.y; s.z += v.z; s.w += v.w;
        mx.x = fmaxf(mx.x, v.x); mx.y = fmaxf(mx.y, v.y);
        mx.z = fmaxf(mx.z, v.z); mx.w = fmaxf(mx.w, v.w);
    }
    __shared__ float4 ls[4][64], lm[4][64];
    ls[wv][l] = s; lm[wv][l] = mx;
    __syncthreads();
    if (wv == 0) {
#pragma unroll
        for (int w = 1; w < 4; w++) {
            float4 a = ls[w][l], m2 = lm[w][l];
            s.x += a.x; s.y += a.y; s.z += a.z; s.w += a.w;
            mx.x = fmaxf(mx.x, m2.x); mx.y = fmaxf(mx.y, m2.y);
            mx.z = fmaxf(mx.z, m2.z); mx.w = fmaxf(mx.w, m2.w);
        }
        ((float4*)psum)[(b * NSL + sl) * 64 + l] = s;
        ((float4*)pmax)[(b * NSL + sl) * 64 + l] = mx;
    }
    // ---- completion protocol (rocPRIM last-block pattern) ----
    __threadfence();               // release partial writes (device scope)
    __syncthreads();
    __shared__ unsigned lastv;
    if (threadIdx.x == 0) lastv = atomicAdd(&cnt[b], 1u);
    __syncthreads();
    if (lastv != NSL - 1) return;
    __threadfence();               // acquire other blocks' partials

    // ---- FC for batch b (this block only) ----
    const int tid = threadIdx.x;
    __shared__ float avg[CC], mxs[CC], hsum[16];
    float s2 = 0.f, mx2 = -1e30f;
    for (int k = 0; k < NSL; k++) {
        s2 += psum[(b * NSL + k) * CC + tid];
        mx2 = fmaxf(mx2, pmax[(b * NSL + k) * CC + tid]);
    }
    avg[tid] = s2 * (1.f / 3136.f);
    mxs[tid] = mx2;
    __syncthreads();
    const int r = tid >> 4, l2 = tid & 15;
    float pa = 0.f, pm = 0.f;
    for (int j = 0; j < 16; j++) {
        float w = w1[r * CC + l2 * 16 + j];
        pa += avg[l2 * 16 + j] * w;
        pm += mxs[l2 * 16 + j] * w;
    }
#pragma unroll
    for (int d = 1; d < 16; d <<= 1) { pa += __shfl_xor(pa, d); pm += __shfl_xor(pm, d); }
    if (l2 == 0) hsum[r] = fmaxf(pa, 0.f) + fmaxf(pm, 0.f);
    __syncthreads();
    float o = 0.f;
#pragma unroll
    for (int r2 = 0; r2 < 16; r2++) o += hsum[r2] * w2[tid * 16 + r2];
    gate[b * CC + tid] = sigmoidf(o);
}

// -------------------- K2: per-position channel mean/max + delta -----------
// grid (196, 32): each wave handles 4 positions; loads issued before reduce.
__global__ void k_pos_reduce(const float* __restrict__ x, const float* __restrict__ gate,
                             const float* __restrict__ dw, const float* __restrict__ db,
                             float* __restrict__ m, float* __restrict__ cmax,
                             float4* __restrict__ mdd) {
    const int wv = threadIdx.x >> 6, l = threadIdx.x & 63;
    const int b = blockIdx.y;
    const float4 g = ((const float4*)gate)[b * 64 + l];
    const float dwv = dw[0], dbv = db[0];
    const int pos0 = b * LL + blockIdx.x * 16 + wv;
    float4 v[4];
#pragma unroll
    for (int k = 0; k < 4; k++) v[k] = ((const float4*)x)[(size_t)(pos0 + 4 * k) * 64 + l];
    float s[4], mm[4];
#pragma unroll
    for (int k = 0; k < 4; k++) {
        float ax = v[k].x * g.x, ay = v[k].y * g.y, az = v[k].z * g.z, aw = v[k].w * g.w;
        s[k]  = ax + ay + az + aw;
        mm[k] = fmaxf(fmaxf(ax, ay), fmaxf(az, aw));
    }
#pragma unroll
    for (int d = 1; d < 64; d <<= 1) {
#pragma unroll
        for (int k = 0; k < 4; k++) {
            s[k] += __shfl_xor(s[k], d);
            mm[k] = fmaxf(mm[k], __shfl_xor(mm[k], d));
        }
    }
    if (l == 0) {
#pragma unroll
        for (int k = 0; k < 4; k++) {
            const int pos = pos0 + 4 * k;
            float mv = s[k] * (1.f / 256.f);
            m[pos] = mv;
            cmax[pos] = mm[k];
            float dl = softplusf(mv * dwv + dbv);
            mdd[pos] = make_float4(mv, dl, dl * mv, 0.f);
        }
    }
}

// -------------------- K3: fused S6 scan (blocks 0..31) + LSA (32..63) -----
__global__ void k_gsa2(const float4* __restrict__ mdd,
                       const float* __restrict__ m, const float* __restrict__ cmax,
                       const float* __restrict__ Bw, const float* __restrict__ Bb,
                       const float* __restrict__ Cw, const float* __restrict__ Cb,
                       const float* __restrict__ A,  const float* __restrict__ wc,
                       float* __restrict__ sy, float* __restrict__ ssg) {
    __shared__ __align__(16) char smem[60928];
    const int tid = threadIdx.x;
    if (blockIdx.x < BB) {
        const int b = blockIdx.x;
        float4* mddl = (float4*)smem;
        float*  Pl   = (float*)(smem + 50176);
        float*  Ql   = (float*)(smem + 50176 + 3584);
        float*  hl   = (float*)(smem + 50176 + 7168);
        for (int i = tid; i < LL; i += 896) mddl[i] = mdd[b * LL + i];
        __syncthreads();
        const int g = tid >> 4, s = tid & 15;
        const float As = A[s], Bws = Bw[s], Bbs = Bb[s];
        const float Cws = Cw[s], Cbs = Cb[s];
        float sumd = 0.f, Q = 0.f;
        for (int t = 0; t < CHL; t++) {
            float4 md = mddl[g * CHL + t];
            float a = __expf(md.y * As);
            Q = a * Q + md.z * (md.x * Bws + Bbs);
            sumd += md.y;
        }
        Pl[g * 16 + s] = __expf(sumd * As);
        Ql[g * 16 + s] = Q;
        __syncthreads();
        if (g == 0) {
            float h = 0.f;
            for (int ch = 0; ch < NCH; ch++) {
                hl[ch * 16 + s] = h;
                h = Pl[ch * 16 + s] * h + Ql[ch * 16 + s];
            }
        }
        __syncthreads();
        float h = hl[g * 16 + s];
        for (int t = 0; t < CHL; t++) {
            float4 md = mddl[g * CHL + t];
            float a = __expf(md.y * As);
            h = a * h + md.z * (md.x * Bws + Bbs);
            float p = h * (md.x * Cws + Cbs);
#pragma unroll
            for (int d = 1; d < 16; d <<= 1) p += __shfl_xor(p, d);
            if (s == 0) sy[b * LL + g * CHL + t] = sigmoidf(p);
        }
    } else {
        const int b = blockIdx.x - BB;
        float* ml = (float*)smem;
        float* cl = (float*)(smem + 12544);
        float* wl = (float*)(smem + 25088);
        for (int i = tid; i < LL; i += 896) {
            ml[i] = m[b * LL + i];
            cl[i] = cmax[b * LL + i];
        }
        if (tid < 98) wl[tid] = wc[tid];
        __syncthreads();
        for (int pos = tid; pos < LL; pos += 896) {
            const int h0 = pos / WWI, w0 = pos - h0 * WWI;
            float acc = 0.f;
#pragma unroll
            for (int kh = 0; kh < 7; kh++) {
                int hh = h0 + kh - 3;
                if ((unsigned)hh >= (unsigned)HHI) continue;
                const int rb = hh * WWI;
#pragma unroll
                for (int kw = 0; kw < 7; kw++) {
                    int ww = w0 + kw - 3;
                    if ((unsigned)ww >= (unsigned)WWI) continue;
                    acc += ml[rb + ww] * wl[(kh * 7 + kw) * 2]
                         + cl[rb + ww] * wl[(kh * 7 + kw) * 2 + 1];
                }
            }
            ssg[b * LL + pos] = sigmoidf(acc);
        }
    }
}

// -------------------- K4: BN partial stats per (b,slice) ------------------
// grid (32,98), block 256; all 8 position-loads issued before accumulation.
__global__ void k_bnstat(const float* __restrict__ x, const float* __restrict__ gate,
                         const float* __restrict__ sy, const float* __restrict__ ssg,
                         float* __restrict__ pb) {
    const int b = blockIdx.x, sl = blockIdx.y;
    const int wv = threadIdx.x >> 6, l = threadIdx.x & 63;
    const float4* x4 = (const float4*)x;
    const float4 g = ((const float4*)gate)[b * 64 + l];
    const int pos0 = b * LL + sl * 32 + wv;
    float4 v[8];
    float g2[8];
#pragma unroll
    for (int k = 0; k < 8; k++) {
        const int pos = pos0 + 4 * k;
        v[k] = x4[(size_t)pos * 64 + l];
        g2[k] = sy[pos] + ssg[pos];
    }
    float4 s = make_float4(0.f, 0.f, 0.f, 0.f);
    float4 q = make_float4(0.f, 0.f, 0.f, 0.f);
#pragma unroll
    for (int k = 0; k < 8; k++) {
        float fx = v[k].x * g.x * g2[k], fy = v[k].y * g.y * g2[k];
        float fz = v[k].z * g.z * g2[k], fw = v[k].w * g.w * g2[k];
        s.x += fx; s.y += fy; s.z += fz; s.w += fw;
        q.x += fx * fx; q.y += fy * fy; q.z += fz * fz; q.w += fw * fw;
    }
    __shared__ float4 ls[4][64], lq[4][64];
    ls[wv][l] = s; lq[wv][l] = q;
    __syncthreads();
    if (wv == 0) {
#pragma unroll
        for (int w = 1; w < 4; w++) {
            float4 a = ls[w][l], c = lq[w][l];
            s.x += a.x; s.y += a.y; s.z += a.z; s.w += a.w;
            q.x += c.x; q.y += c.y; q.z += c.z; q.w += c.w;
        }
        ((float4*)pb)[(b * NSL + sl) * 128 + l] = s;
        ((float4*)pb)[(b * NSL + sl) * 128 + 64 + l] = q;
    }
}

// -------------------- K5: BN reduce (64 blocks) + last-block finalize -----
__global__ void k_bnred2(const float* __restrict__ pb,
                         const float* __restrict__ gamma, const float* __restrict__ beta,
                         float* __restrict__ partial, float* __restrict__ sc,
                         float* __restrict__ sh, unsigned* __restrict__ cnt) {
    const int i = blockIdx.x, tid = threadIdx.x;   // 64 blocks x 512
    const float* p = pb + (size_t)i * 49 * 512 + tid;
    float acc = 0.f;
#pragma unroll
    for (int r = 0; r < 49; r++) acc += p[(size_t)r * 512];
    partial[i * 512 + tid] = acc;
    __threadfence();
    __syncthreads();
    __shared__ unsigned lastv;
    if (tid == 0) lastv = atomicAdd(&cnt[32], 1u);
    __syncthreads();
    if (lastv != 63) return;
    __threadfence();
    float a2 = 0.f;
#pragma unroll
    for (int k = 0; k < 64; k++) a2 += partial[k * 512 + tid];
    __shared__ float red[512];
    red[tid] = a2;
    __syncthreads();
    if (tid < 256) {
        const float inv = 1.f / (float)(BB * LL);
        float mean = red[tid] * inv;
        float var  = red[256 + tid] * inv - mean * mean;
        float sv = gamma[tid] * rsqrtf(var + EPSV);
        sc[tid] = sv;
        sh[tid] = beta[tid] - mean * sv;
    }
}

// -------------------- K6: normalize + ReLU + nontemporal write ------------
// grid (196, 32): each wave handles 4 positions; loads issued up front.
__global__ void k_final(const float* __restrict__ x, const float* __restrict__ gate,
                        const float* __restrict__ sy, const float* __restrict__ ssg,
                        const float* __restrict__ sc, const float* __restrict__ sh,
                        float* __restrict__ out) {
    const int wv = threadIdx.x >> 6, l = threadIdx.x & 63;
    const int b = blockIdx.y;
    const float4 scv = ((const float4*)sc)[l];
    const float4 shv = ((const float4*)sh)[l];
    const float4 g = ((const float4*)gate)[b * 64 + l];
    const int pos0 = b * LL + blockIdx.x * 16 + wv;
    float4 v[4];
    float g2[4];
#pragma unroll
    for (int k = 0; k < 4; k++) {
        const int pos = pos0 + 4 * k;
        v[k] = ((const float4*)x)[(size_t)pos * 64 + l];
        g2[k] = sy[pos] + ssg[pos];
    }
#pragma unroll
    for (int k = 0; k < 4; k++) {
        const int pos = pos0 + 4 * k;
        vfloat4 o;
        o.x = fmaxf(v[k].x * g.x * g2[k] * scv.x + shv.x, 0.f);
        o.y = fmaxf(v[k].y * g.y * g2[k] * scv.y + shv.y, 0.f);
        o.z = fmaxf(v[k].z * g.z * g2[k] * scv.z + shv.z, 0.f);
        o.w = fmaxf(v[k].w * g.w * g2[k] * scv.w + shv.w, 0.f);
        __builtin_nontemporal_store(o, (vfloat4*)out + (size_t)pos * 64 + l);
    }
}

extern "C" void kernel_launch(void* const* d_in, const int* in_sizes, int n_in,
                              void* d_out, int out_size, void* d_ws, size_t ws_size,
                              hipStream_t stream) {
    const float* x     = (const float*)d_in[0];
    const float* ca_w1 = (const float*)d_in[1];
    const float* ca_w2 = (const float*)d_in[2];
    const float* lsa_w = (const float*)d_in[3];
    const float* A     = (const float*)d_in[4];
    const float* d_wp  = (const float*)d_in[5];
    const float* d_bp  = (const float*)d_in[6];
    const float* B_wp  = (const float*)d_in[7];
    const float* B_bp  = (const float*)d_in[8];
    const float* C_wp  = (const float*)d_in[9];
    const float* C_bp  = (const float*)d_in[10];
    const float* bn_g  = (const float*)d_in[11];
    const float* bn_b  = (const float*)d_in[12];
    float* out = (float*)d_out;

    // Large partial buffers live in d_out (fully overwritten by k_final).
    float* psum = out;                         // 32*98*256
    float* pmax = psum + BB * NSL * CC;        // 32*98*256
    float* pb   = pmax + BB * NSL * CC;        // 32*98*512  (total 3.2M floats < 25.7M)

    float* ws       = (float*)d_ws;
    float4* mdd     = (float4*)ws;             // 100352 float4
    float* gate     = ws + 401408;             // 8192
    float* m        = gate + 8192;             // 100352
    float* cmax     = m + 100352;              // 100352
    float* sy       = cmax + 100352;           // 100352
    float* ssg      = sy + 100352;             // 100352
    float* scv      = ssg + 100352;            // 256
    float* shv      = scv + 256;               // 256
    float* partial  = shv + 256;               // 64*512 = 32768
    unsigned* cnt   = (unsigned*)(partial + 32768);  // 33 counters

    hipMemsetAsync(cnt, 0, 33 * sizeof(unsigned), stream);
    k_ca<<<dim3(BB, NSL), 256, 0, stream>>>(x, ca_w1, ca_w2, psum, pmax, gate, cnt);
    k_pos_reduce<<<dim3(LL / 16, BB), 256, 0, stream>>>(x, gate, d_wp, d_bp, m, cmax, mdd);
    k_gsa2<<<2 * BB, 896, 0, stream>>>(mdd, m, cmax, B_wp, B_bp, C_wp, C_bp, A, lsa_w, sy, ssg);
    k_bnstat<<<dim3(BB, NSL), 256, 0, stream>>>(x, gate, sy, ssg, pb);
    k_bnred2<<<64, 512, 0, stream>>>(pb, bn_g, bn_b, partial, scv, shv, cnt);
    k_final<<<dim3(LL / 16, BB), 256, 0, stream>>>(x, gate, sy, ssg, scv, shv, out);
}

// Round 12
// 123.559 us; speedup vs baseline: 3.8371x; 3.8371x over previous
//
#include <hip/hip_runtime.h>
#include <math.h>

#define BB   32
#define HHI  56
#define WWI  56
#define CC   256
#define LL   3136      // H*W
#define SS   16
#define NCH  56        // chunks per batch
#define CHL  56        // chunk length
#define NSL  98        // spatial slices for reductions (32 positions each)
#define EPSV 1e-5f

typedef float vfloat4 __attribute__((ext_vector_type(4)));

__device__ __forceinline__ float softplusf(float z) {
    return fmaxf(z, 0.f) + __logf(1.f + __expf(-fabsf(z)));
}
__device__ __forceinline__ float sigmoidf(float z) {
    return 1.f / (1.f + __expf(-z));
}

// -------------------- K1: per-(b,slice) spatial partial sum/max over C ----
// grid (32,98), block 256 (4 waves). LDS combine -> 1 partial per block.
// NOTE: no cross-block fences — device-scope __threadfence costs an L2
// writeback per block on gfx950 (R11: 3136 fences -> 520us kernel).
__global__ void k_ca_partial(const float* __restrict__ x,
                             float* __restrict__ psum, float* __restrict__ pmax) {
    const int b = blockIdx.x, sl = blockIdx.y;
    const int wv = threadIdx.x >> 6, l = threadIdx.x & 63;
    const float4* x4 = (const float4*)x;
    const size_t base = ((size_t)b * LL + sl * 32) * 64;
    float4 v[8];
#pragma unroll
    for (int k = 0; k < 8; k++) v[k] = x4[base + (size_t)(k * 4 + wv) * 64 + l];
    float4 s  = make_float4(0.f, 0.f, 0.f, 0.f);
    float4 mx = make_float4(-1e30f, -1e30f, -1e30f, -1e30f);
#pragma unroll
    for (int k = 0; k < 8; k++) {
        s.x += v[k].x; s.y += v[k].y; s.z += v[k].z; s.w += v[k].w;
        mx.x = fmaxf(mx.x, v[k].x); mx.y = fmaxf(mx.y, v[k].y);
        mx.z = fmaxf(mx.z, v[k].z); mx.w = fmaxf(mx.w, v[k].w);
    }
    __shared__ float4 ls[4][64], lm[4][64];
    ls[wv][l] = s; lm[wv][l] = mx;
    __syncthreads();
    if (wv == 0) {
#pragma unroll
        for (int w = 1; w < 4; w++) {
            float4 a = ls[w][l], m2 = lm[w][l];
            s.x += a.x; s.y += a.y; s.z += a.z; s.w += a.w;
            mx.x = fmaxf(mx.x, m2.x); mx.y = fmaxf(mx.y, m2.y);
            mx.z = fmaxf(mx.z, m2.z); mx.w = fmaxf(mx.w, m2.w);
        }
        ((float4*)psum)[(b * NSL + sl) * 64 + l] = s;
        ((float4*)pmax)[(b * NSL + sl) * 64 + l] = mx;
    }
}

// -------------------- K2: combine partials + ChannelAttention FC ----------
__global__ void k_ca_fc(const float* __restrict__ psum, const float* __restrict__ pmax,
                        const float* __restrict__ w1, const float* __restrict__ w2,
                        float* __restrict__ gate) {
    const int b = blockIdx.x, tid = threadIdx.x;
    __shared__ float avg[CC], mxs[CC], hsum[16];
    float s = 0.f, mx = -1e30f;
    for (int k = 0; k < NSL; k++) {
        s += psum[(b * NSL + k) * CC + tid];
        mx = fmaxf(mx, pmax[(b * NSL + k) * CC + tid]);
    }
    avg[tid] = s * (1.f / 3136.f);
    mxs[tid] = mx;
    __syncthreads();
    const int r = tid >> 4, l = tid & 15;
    float pa = 0.f, pm = 0.f;
    for (int j = 0; j < 16; j++) {
        float w = w1[r * CC + l * 16 + j];
        pa += avg[l * 16 + j] * w;
        pm += mxs[l * 16 + j] * w;
    }
#pragma unroll
    for (int d = 1; d < 16; d <<= 1) { pa += __shfl_xor(pa, d); pm += __shfl_xor(pm, d); }
    if (l == 0) hsum[r] = fmaxf(pa, 0.f) + fmaxf(pm, 0.f);
    __syncthreads();
    float o = 0.f;
#pragma unroll
    for (int r2 = 0; r2 < 16; r2++) o += hsum[r2] * w2[tid * 16 + r2];
    gate[b * CC + tid] = sigmoidf(o);
}

// -------------------- K3: per-position channel mean/max + delta -----------
// grid (196, 32): each wave handles 4 positions; loads issued before reduce.
__global__ void k_pos_reduce(const float* __restrict__ x, const float* __restrict__ gate,
                             const float* __restrict__ dw, const float* __restrict__ db,
                             float* __restrict__ m, float* __restrict__ cmax,
                             float4* __restrict__ mdd) {
    const int wv = threadIdx.x >> 6, l = threadIdx.x & 63;
    const int b = blockIdx.y;
    const float4 g = ((const float4*)gate)[b * 64 + l];
    const float dwv = dw[0], dbv = db[0];
    const int pos0 = b * LL + blockIdx.x * 16 + wv;
    float4 v[4];
#pragma unroll
    for (int k = 0; k < 4; k++) v[k] = ((const float4*)x)[(size_t)(pos0 + 4 * k) * 64 + l];
    float s[4], mm[4];
#pragma unroll
    for (int k = 0; k < 4; k++) {
        float ax = v[k].x * g.x, ay = v[k].y * g.y, az = v[k].z * g.z, aw = v[k].w * g.w;
        s[k]  = ax + ay + az + aw;
        mm[k] = fmaxf(fmaxf(ax, ay), fmaxf(az, aw));
    }
#pragma unroll
    for (int d = 1; d < 64; d <<= 1) {
#pragma unroll
        for (int k = 0; k < 4; k++) {
            s[k] += __shfl_xor(s[k], d);
            mm[k] = fmaxf(mm[k], __shfl_xor(mm[k], d));
        }
    }
    if (l == 0) {
#pragma unroll
        for (int k = 0; k < 4; k++) {
            const int pos = pos0 + 4 * k;
            float mv = s[k] * (1.f / 256.f);
            m[pos] = mv;
            cmax[pos] = mm[k];
            float dl = softplusf(mv * dwv + dbv);
            mdd[pos] = make_float4(mv, dl, dl * mv, 0.f);
        }
    }
}

// -------------------- K4: fused S6 scan (blocks 0..31) + LSA (32..63) -----
__global__ void k_gsa2(const float4* __restrict__ mdd,
                       const float* __restrict__ m, const float* __restrict__ cmax,
                       const float* __restrict__ Bw, const float* __restrict__ Bb,
                       const float* __restrict__ Cw, const float* __restrict__ Cb,
                       const float* __restrict__ A,  const float* __restrict__ wc,
                       float* __restrict__ sy, float* __restrict__ ssg) {
    __shared__ __align__(16) char smem[60928];
    const int tid = threadIdx.x;
    if (blockIdx.x < BB) {
        const int b = blockIdx.x;
        float4* mddl = (float4*)smem;
        float*  Pl   = (float*)(smem + 50176);
        float*  Ql   = (float*)(smem + 50176 + 3584);
        float*  hl   = (float*)(smem + 50176 + 7168);
        for (int i = tid; i < LL; i += 896) mddl[i] = mdd[b * LL + i];
        __syncthreads();
        const int g = tid >> 4, s = tid & 15;
        const float As = A[s], Bws = Bw[s], Bbs = Bb[s];
        const float Cws = Cw[s], Cbs = Cb[s];
        float sumd = 0.f, Q = 0.f;
        for (int t = 0; t < CHL; t++) {
            float4 md = mddl[g * CHL + t];
            float a = __expf(md.y * As);
            Q = a * Q + md.z * (md.x * Bws + Bbs);
            sumd += md.y;
        }
        Pl[g * 16 + s] = __expf(sumd * As);
        Ql[g * 16 + s] = Q;
        __syncthreads();
        if (g == 0) {
            float h = 0.f;
            for (int ch = 0; ch < NCH; ch++) {
                hl[ch * 16 + s] = h;
                h = Pl[ch * 16 + s] * h + Ql[ch * 16 + s];
            }
        }
        __syncthreads();
        float h = hl[g * 16 + s];
        for (int t = 0; t < CHL; t++) {
            float4 md = mddl[g * CHL + t];
            float a = __expf(md.y * As);
            h = a * h + md.z * (md.x * Bws + Bbs);
            float p = h * (md.x * Cws + Cbs);
#pragma unroll
            for (int d = 1; d < 16; d <<= 1) p += __shfl_xor(p, d);
            if (s == 0) sy[b * LL + g * CHL + t] = sigmoidf(p);
        }
    } else {
        const int b = blockIdx.x - BB;
        float* ml = (float*)smem;
        float* cl = (float*)(smem + 12544);
        float* wl = (float*)(smem + 25088);
        for (int i = tid; i < LL; i += 896) {
            ml[i] = m[b * LL + i];
            cl[i] = cmax[b * LL + i];
        }
        if (tid < 98) wl[tid] = wc[tid];
        __syncthreads();
        for (int pos = tid; pos < LL; pos += 896) {
            const int h0 = pos / WWI, w0 = pos - h0 * WWI;
            float acc = 0.f;
#pragma unroll
            for (int kh = 0; kh < 7; kh++) {
                int hh = h0 + kh - 3;
                if ((unsigned)hh >= (unsigned)HHI) continue;
                const int rb = hh * WWI;
#pragma unroll
                for (int kw = 0; kw < 7; kw++) {
                    int ww = w0 + kw - 3;
                    if ((unsigned)ww >= (unsigned)WWI) continue;
                    acc += ml[rb + ww] * wl[(kh * 7 + kw) * 2]
                         + cl[rb + ww] * wl[(kh * 7 + kw) * 2 + 1];
                }
            }
            ssg[b * LL + pos] = sigmoidf(acc);
        }
    }
}

// -------------------- K5: BN partial stats per (b,slice) ------------------
// grid (32,98), block 256; all 8 position-loads issued before accumulation.
__global__ void k_bnstat(const float* __restrict__ x, const float* __restrict__ gate,
                         const float* __restrict__ sy, const float* __restrict__ ssg,
                         float* __restrict__ pb) {
    const int b = blockIdx.x, sl = blockIdx.y;
    const int wv = threadIdx.x >> 6, l = threadIdx.x & 63;
    const float4* x4 = (const float4*)x;
    const float4 g = ((const float4*)gate)[b * 64 + l];
    const int pos0 = b * LL + sl * 32 + wv;
    float4 v[8];
    float g2[8];
#pragma unroll
    for (int k = 0; k < 8; k++) {
        const int pos = pos0 + 4 * k;
        v[k] = x4[(size_t)pos * 64 + l];
        g2[k] = sy[pos] + ssg[pos];
    }
    float4 s = make_float4(0.f, 0.f, 0.f, 0.f);
    float4 q = make_float4(0.f, 0.f, 0.f, 0.f);
#pragma unroll
    for (int k = 0; k < 8; k++) {
        float fx = v[k].x * g.x * g2[k], fy = v[k].y * g.y * g2[k];
        float fz = v[k].z * g.z * g2[k], fw = v[k].w * g.w * g2[k];
        s.x += fx; s.y += fy; s.z += fz; s.w += fw;
        q.x += fx * fx; q.y += fy * fy; q.z += fz * fz; q.w += fw * fw;
    }
    __shared__ float4 ls[4][64], lq[4][64];
    ls[wv][l] = s; lq[wv][l] = q;
    __syncthreads();
    if (wv == 0) {
#pragma unroll
        for (int w = 1; w < 4; w++) {
            float4 a = ls[w][l], c = lq[w][l];
            s.x += a.x; s.y += a.y; s.z += a.z; s.w += a.w;
            q.x += c.x; q.y += c.y; q.z += c.z; q.w += c.w;
        }
        ((float4*)pb)[(b * NSL + sl) * 128 + l] = s;
        ((float4*)pb)[(b * NSL + sl) * 128 + 64 + l] = q;
    }
}

// -------------------- K6a: BN reduce stage 1 (coalesced, unrolled) --------
// grid 64, block 512. Block i sums rows [i*49, i*49+49) of pb[3136][512].
__global__ void k_bnred(const float* __restrict__ pb, float* __restrict__ partial) {
    const int i = blockIdx.x, tid = threadIdx.x;
    const float* p = pb + (size_t)i * 49 * 512 + tid;
    float acc = 0.f;
#pragma unroll
    for (int r = 0; r < 49; r++) acc += p[(size_t)r * 512];
    partial[i * 512 + tid] = acc;
}

// -------------------- K6b: BN final reduce + scale/shift ------------------
// 1 block, 512 threads. partial[64][512] -> scv/shv[256].
__global__ void k_bnfin(const float* __restrict__ partial,
                        const float* __restrict__ gamma, const float* __restrict__ beta,
                        float* __restrict__ sc, float* __restrict__ sh) {
    const int tid = threadIdx.x;
    float acc = 0.f;
#pragma unroll
    for (int i = 0; i < 64; i++) acc += partial[i * 512 + tid];
    __shared__ float red[512];
    red[tid] = acc;
    __syncthreads();
    if (tid < 256) {
        const float inv = 1.f / (float)(BB * LL);
        float mean = red[tid] * inv;
        float var  = red[256 + tid] * inv - mean * mean;
        float sv = gamma[tid] * rsqrtf(var + EPSV);
        sc[tid] = sv;
        sh[tid] = beta[tid] - mean * sv;
    }
}

// -------------------- K7: normalize + ReLU + nontemporal write ------------
// grid (196, 32): each wave handles 4 positions; loads issued up front.
__global__ void k_final(const float* __restrict__ x, const float* __restrict__ gate,
                        const float* __restrict__ sy, const float* __restrict__ ssg,
                        const float* __restrict__ sc, const float* __restrict__ sh,
                        float* __restrict__ out) {
    const int wv = threadIdx.x >> 6, l = threadIdx.x & 63;
    const int b = blockIdx.y;
    const float4 scv = ((const float4*)sc)[l];
    const float4 shv = ((const float4*)sh)[l];
    const float4 g = ((const float4*)gate)[b * 64 + l];
    const int pos0 = b * LL + blockIdx.x * 16 + wv;
    float4 v[4];
    float g2[4];
#pragma unroll
    for (int k = 0; k < 4; k++) {
        const int pos = pos0 + 4 * k;
        v[k] = ((const float4*)x)[(size_t)pos * 64 + l];
        g2[k] = sy[pos] + ssg[pos];
    }
#pragma unroll
    for (int k = 0; k < 4; k++) {
        const int pos = pos0 + 4 * k;
        vfloat4 o;
        o.x = fmaxf(v[k].x * g.x * g2[k] * scv.x + shv.x, 0.f);
        o.y = fmaxf(v[k].y * g.y * g2[k] * scv.y + shv.y, 0.f);
        o.z = fmaxf(v[k].z * g.z * g2[k] * scv.z + shv.z, 0.f);
        o.w = fmaxf(v[k].w * g.w * g2[k] * scv.w + shv.w, 0.f);
        __builtin_nontemporal_store(o, (vfloat4*)out + (size_t)pos * 64 + l);
    }
}

extern "C" void kernel_launch(void* const* d_in, const int* in_sizes, int n_in,
                              void* d_out, int out_size, void* d_ws, size_t ws_size,
                              hipStream_t stream) {
    const float* x     = (const float*)d_in[0];
    const float* ca_w1 = (const float*)d_in[1];
    const float* ca_w2 = (const float*)d_in[2];
    const float* lsa_w = (const float*)d_in[3];
    const float* A     = (const float*)d_in[4];
    const float* d_wp  = (const float*)d_in[5];
    const float* d_bp  = (const float*)d_in[6];
    const float* B_wp  = (const float*)d_in[7];
    const float* B_bp  = (const float*)d_in[8];
    const float* C_wp  = (const float*)d_in[9];
    const float* C_bp  = (const float*)d_in[10];
    const float* bn_g  = (const float*)d_in[11];
    const float* bn_b  = (const float*)d_in[12];
    float* out = (float*)d_out;

    // Large partial buffers live in d_out (fully overwritten by k_final).
    float* psum = out;                         // 32*98*256
    float* pmax = psum + BB * NSL * CC;        // 32*98*256
    float* pb   = pmax + BB * NSL * CC;        // 32*98*512  (total 3.2M floats < 25.7M)

    float* ws      = (float*)d_ws;
    float4* mdd    = (float4*)ws;              // 100352 float4 (16B aligned at base)
    float* gate    = ws + 401408;              // 8192
    float* m       = gate + 8192;              // 100352
    float* cmax    = m + 100352;               // 100352
    float* sy      = cmax + 100352;            // 100352
    float* ssg     = sy + 100352;              // 100352
    float* scv     = ssg + 100352;             // 256
    float* shv     = scv + 256;                // 256
    float* partial = shv + 256;                // 64*512 = 32768

    k_ca_partial<<<dim3(BB, NSL), 256, 0, stream>>>(x, psum, pmax);
    k_ca_fc<<<BB, 256, 0, stream>>>(psum, pmax, ca_w1, ca_w2, gate);
    k_pos_reduce<<<dim3(LL / 16, BB), 256, 0, stream>>>(x, gate, d_wp, d_bp, m, cmax, mdd);
    k_gsa2<<<2 * BB, 896, 0, stream>>>(mdd, m, cmax, B_wp, B_bp, C_wp, C_bp, A, lsa_w, sy, ssg);
    k_bnstat<<<dim3(BB, NSL), 256, 0, stream>>>(x, gate, sy, ssg, pb);
    k_bnred<<<64, 512, 0, stream>>>(pb, partial);
    k_bnfin<<<1, 512, 0, stream>>>(partial, bn_g, bn_b, scv, shv);
    k_final<<<dim3(LL / 16, BB), 256, 0, stream>>>(x, gate, sy, ssg, scv, shv, out);
}